// Round 14
// baseline (113.449 us; speedup 1.0000x reference)
//
#include <hip/hip_runtime.h>
#include <math.h>

#define HH 16
#define DM 1024
#define DK 64
#define NE 40001
#define NB 2
#define NQS 512
#define NKS 512

typedef unsigned short ushort_t;
typedef __attribute__((ext_vector_type(8))) short short8v;
typedef __attribute__((ext_vector_type(4))) float f32x4;

__device__ __forceinline__ ushort_t f2bf(float f) {
    union { float f; unsigned u; } v; v.f = f;
    unsigned r = v.u + 0x7FFFu + ((v.u >> 16) & 1u);
    return (ushort_t)(r >> 16);
}
__device__ __forceinline__ unsigned pack2(float a, float b) {
    return (unsigned)f2bf(a) | ((unsigned)f2bf(b) << 16);
}
__device__ __forceinline__ float asf(unsigned u) {
    union { unsigned u; float f; } v; v.u = u; return v.f;
}

// ---------------------------------------------------------------------------
// Kernel 1 (fused): proj ∥ Wo-transpose ∥ QKV-GEMM, block-interleaved.
// prep's ~40us window is implementation-invariant (5 rewrites, r6-r13) —
// so hide the compute-bound QKV GEMM inside it instead of serializing after.
// GEMM reads fp32 query/key/value AND fp32 Wq/Wk/Wv directly (convert during
// LDS staging; B transpose-staged) -> no dependency on proj, no intermediate
// qc/kc/vc/wqt/wkt/wvt buffers (~44 MB traffic removed).
//   even bids            : proj block (bid>>1, 0..1023) — persistent stride
//   odd bids, u<768      : QKV GEMM block u (z=u>>8, 64x64 tile, BK=64)
//   odd bids, u>=768     : Wo transpose tile u-768 (0..255) for ogemm
// ---------------------------------------------------------------------------
#define PROJ_F4   (NE * 64)            // 2,560,064 float4 per table
#define PROJ_TOT  (2 * PROJ_F4)        // 5,120,128
#define K1_BLKS   2048

__global__ __launch_bounds__(256, 4) void fused1_k(
    const float* __restrict__ xt, const float* __restrict__ yt,
    const float* __restrict__ Wb,
    const float* __restrict__ wq, const float* __restrict__ wk,
    const float* __restrict__ wv, const float* __restrict__ wo,
    const float* __restrict__ query, const float* __restrict__ key, const float* __restrict__ value,
    const float* __restrict__ bq, const float* __restrict__ bk, const float* __restrict__ bv,
    ushort_t* __restrict__ xproj, ushort_t* __restrict__ yproj,
    ushort_t* __restrict__ wot,
    ushort_t* __restrict__ qbh, ushort_t* __restrict__ kbh, ushort_t* __restrict__ vtb)
{
    __shared__ __align__(16) unsigned char smem[18944];
    ushort_t (*As)[72] = (ushort_t(*)[72])smem;          // GEMM A tile (9216 B)
    ushort_t (*Bs)[72] = (ushort_t(*)[72])(smem + 9472); // GEMM B tile
    float (*ls)[68] = (float(*)[68])smem;                // wot tile (17408 B)

    const int bid = blockIdx.x;
    const int tid = threadIdx.x;

    if (!(bid & 1)) {
        // ---------- proj: persistent grid-stride + 4-lane shuffle reduce ----------
        const int pb = bid >> 1;                   // 0..1023
        const int c = tid & 3;
        const float4 wq4 = ((const float4*)Wb)[c];
#pragma unroll 4
        for (int f4 = pb * 256 + tid; f4 < PROJ_TOT; f4 += 1024 * 256) {
            const int tsel = (f4 >= PROJ_F4);
            const int g = tsel ? f4 - PROJ_F4 : f4;
            const float* tab = tsel ? yt : xt;
            float4 v = ((const float4*)tab)[g];
            float p = v.x * wq4.x + v.y * wq4.y + v.z * wq4.z + v.w * wq4.w;
            p += __shfl_xor(p, 1);
            p += __shfl_xor(p, 2);                 // full 16-elem dot in all 4 lanes
            if (c == 0) {
                ushort_t* dst = tsel ? yproj : xproj;
                const int i = g >> 6, h = (g >> 2) & 15;
                dst[i * 16 + h] = f2bf(p);
            }
        }
        return;
    }

    const int u = bid >> 1;                        // 0..1023
    if (u >= 768) {
        // ---------- Wo transpose-convert tile (for ogemm) ----------
        const int rem = u - 768;                   // 0..255
        const int k0 = (rem >> 4) * 64, n0 = (rem & 15) * 64;
#pragma unroll
        for (int j = 0; j < 4; ++j) {
            int r = (tid >> 4) + j * 16;
            int c2 = (tid & 15) * 4;
            float4 v = *(const float4*)(wo + (k0 + r) * 1024 + n0 + c2);
            *(float4*)&ls[r][c2] = v;
        }
        __syncthreads();
        const int n = tid >> 2, kq = (tid & 3) * 16;
        float e[16];
#pragma unroll
        for (int j = 0; j < 16; ++j) e[j] = ls[kq + j][n];
        uint4 o0, o1;
        o0.x = pack2(e[0], e[1]);   o0.y = pack2(e[2], e[3]);
        o0.z = pack2(e[4], e[5]);   o0.w = pack2(e[6], e[7]);
        o1.x = pack2(e[8], e[9]);   o1.y = pack2(e[10], e[11]);
        o1.z = pack2(e[12], e[13]); o1.w = pack2(e[14], e[15]);
        ushort_t* dp = wot + (n0 + n) * 1024 + k0 + kq;
        *(uint4*)(dp)     = o0;
        *(uint4*)(dp + 8) = o1;
        return;
    }

    // ---------- QKV GEMM: A fp32 (x), B fp32 (W, transpose-staged) ----------
    const int z = u >> 8, by = (u >> 4) & 15, bx = u & 15;
    const float* Af = (z == 0) ? query : ((z == 1) ? key : value);
    const float* Wf = (z == 0) ? wq : ((z == 1) ? wk : wv);
    const float* bi = (z == 0) ? bq : ((z == 1) ? bk : bv);
    ushort_t* Yh = (z == 0) ? qbh : ((z == 1) ? kbh : vtb);
    const int m0 = by * 64, n0 = bx * 64;
    const int lane = tid & 63, w = tid >> 6;
    const int wm = w >> 1, wn = w & 1;
    const int srow = tid >> 2, scg = (tid & 3) * 16;   // A staging
    const int br_ = tid >> 4, bc = (tid & 15) * 4;     // B staging

    f32x4 acc[2][2] = {};
    float4 arf0, arf1, arf2, arf3;
    float4 brf0, brf1, brf2, brf3;

    auto loadA = [&](int kk) {
        const float* ap = Af + (m0 + srow) * 1024 + kk + scg;
        arf0 = *(const float4*)(ap);
        arf1 = *(const float4*)(ap + 4);
        arf2 = *(const float4*)(ap + 8);
        arf3 = *(const float4*)(ap + 12);
    };
    auto loadB = [&](int kk) {
        brf0 = *(const float4*)(Wf + (kk + br_)      * 1024 + n0 + bc);
        brf1 = *(const float4*)(Wf + (kk + br_ + 16) * 1024 + n0 + bc);
        brf2 = *(const float4*)(Wf + (kk + br_ + 32) * 1024 + n0 + bc);
        brf3 = *(const float4*)(Wf + (kk + br_ + 48) * 1024 + n0 + bc);
    };
    loadA(0); loadB(0);

    const int fr = lane & 15;            // frag row/col within 16
    const int ko = (lane >> 4) * 8;      // k offset within 32

    for (int k0 = 0; k0 < 1024; k0 += 64) {
        __syncthreads();
        {   // A convert + store
            uint4 w0, w1;
            w0.x = pack2(arf0.x, arf0.y); w0.y = pack2(arf0.z, arf0.w);
            w0.z = pack2(arf1.x, arf1.y); w0.w = pack2(arf1.z, arf1.w);
            w1.x = pack2(arf2.x, arf2.y); w1.y = pack2(arf2.z, arf2.w);
            w1.z = pack2(arf3.x, arf3.y); w1.w = pack2(arf3.z, arf3.w);
            *(uint4*)&As[srow][scg]     = w0;
            *(uint4*)&As[srow][scg + 8] = w1;
        }
        {   // B transpose-convert store: Bs[n][k] = W[k][n]
            Bs[bc + 0][br_] = f2bf(brf0.x); Bs[bc + 1][br_] = f2bf(brf0.y);
            Bs[bc + 2][br_] = f2bf(brf0.z); Bs[bc + 3][br_] = f2bf(brf0.w);
            Bs[bc + 0][br_ + 16] = f2bf(brf1.x); Bs[bc + 1][br_ + 16] = f2bf(brf1.y);
            Bs[bc + 2][br_ + 16] = f2bf(brf1.z); Bs[bc + 3][br_ + 16] = f2bf(brf1.w);
            Bs[bc + 0][br_ + 32] = f2bf(brf2.x); Bs[bc + 1][br_ + 32] = f2bf(brf2.y);
            Bs[bc + 2][br_ + 32] = f2bf(brf2.z); Bs[bc + 3][br_ + 32] = f2bf(brf2.w);
            Bs[bc + 0][br_ + 48] = f2bf(brf3.x); Bs[bc + 1][br_ + 48] = f2bf(brf3.y);
            Bs[bc + 2][br_ + 48] = f2bf(brf3.z); Bs[bc + 3][br_ + 48] = f2bf(brf3.w);
        }
        __syncthreads();
        if (k0 + 64 < 1024) { loadA(k0 + 64); loadB(k0 + 64); }
#pragma unroll
        for (int ks = 0; ks < 64; ks += 32) {
            short8v af0 = *(const short8v*)&As[wm * 32 + fr][ks + ko];
            short8v af1 = *(const short8v*)&As[wm * 32 + 16 + fr][ks + ko];
            short8v bf0 = *(const short8v*)&Bs[wn * 32 + fr][ks + ko];
            short8v bf1 = *(const short8v*)&Bs[wn * 32 + 16 + fr][ks + ko];
            acc[0][0] = __builtin_amdgcn_mfma_f32_16x16x32_bf16(af0, bf0, acc[0][0], 0, 0, 0);
            acc[0][1] = __builtin_amdgcn_mfma_f32_16x16x32_bf16(af0, bf1, acc[0][1], 0, 0, 0);
            acc[1][0] = __builtin_amdgcn_mfma_f32_16x16x32_bf16(af1, bf0, acc[1][0], 0, 0, 0);
            acc[1][1] = __builtin_amdgcn_mfma_f32_16x16x32_bf16(af1, bf1, acc[1][1], 0, 0, 0);
        }
    }

    const int cr = (lane >> 4) * 4;
    const int cc = lane & 15;
#pragma unroll
    for (int m = 0; m < 2; ++m) {
#pragma unroll
        for (int n = 0; n < 2; ++n) {
            int grow = m0 + wm * 32 + m * 16 + cr;
            int gcol = n0 + wn * 32 + n * 16 + cc;
            float bv = bi[gcol];
            int hh = gcol >> 6, dd = gcol & 63;
            if (z == 0) {
#pragma unroll
                for (int j = 0; j < 4; ++j) {
                    int r = grow + j, bb_ = r >> 9, nn = r & 511;
                    Yh[((bb_ * HH + hh) * NQS + nn) * DK + dd] = f2bf(acc[m][n][j] + bv);
                }
            } else if (z == 1) {
                // K pre-scaled by 1/sqrt(DK) = 0.125 (exact power-of-two)
#pragma unroll
                for (int j = 0; j < 4; ++j) {
                    int r = grow + j, bb_ = r >> 9, nn = r & 511;
                    Yh[((bb_ * HH + hh) * NQS + nn) * DK + dd] = f2bf((acc[m][n][j] + bv) * 0.125f);
                }
            } else {
                // V: (B,H,64,N) bf16 transposed
#pragma unroll
                for (int j = 0; j < 4; ++j) {
                    int r = grow + j, bb_ = r >> 9, nn = r & 511;
                    Yh[((bb_ * HH + hh) * DK + dd) * NKS + nn] = f2bf(acc[m][n][j] + bv);
                }
            }
        }
    }
}

// ---------------------------------------------------------------------------
// Kernel 2: bias precompute in MFMA-fragment layout (round-3 verified).
// ---------------------------------------------------------------------------
__global__ __launch_bounds__(256) void bias_k(
    const ushort_t* __restrict__ xproj, const ushort_t* __restrict__ yproj,
    const float* __restrict__ qx, const float* __restrict__ qy,
    const float* __restrict__ kx, const float* __restrict__ ky,
    const float* __restrict__ bbp,
    ushort_t* __restrict__ biasf)
{
    const int tid = threadIdx.x;
    const int r = blockIdx.x;              // 0..2047
    const int b = r >> 10;
    const int kt = (r >> 5) & 31, qt = r & 31;
    const int ql = tid & 15, kl = tid >> 4;
    const int qg = qt * 16 + ql, kg = kt * 16 + kl;

    float dx = qx[b * NKS + kg] - kx[b * NQS + qg];
    float dy = qy[b * NKS + kg] - ky[b * NQS + qg];
    int ix = (int)rintf((fminf(fmaxf(dx, -1000.f), 1000.f) + 1000.f) * 20.f);
    int iy = (int)rintf((fminf(fmaxf(dy, -1000.f), 1000.f) + 1000.f) * 20.f);
    const float bb = bbp[0];

    uint4 xw0 = *(const uint4*)(xproj + ix * 16);
    uint4 xw1 = *(const uint4*)(xproj + ix * 16 + 8);
    uint4 yw0 = *(const uint4*)(yproj + iy * 16);
    uint4 yw1 = *(const uint4*)(yproj + iy * 16 + 8);

    float xa[16], ya[16];
    {
        unsigned uu[8] = {xw0.x, xw0.y, xw0.z, xw0.w, xw1.x, xw1.y, xw1.z, xw1.w};
        unsigned vv[8] = {yw0.x, yw0.y, yw0.z, yw0.w, yw1.x, yw1.y, yw1.z, yw1.w};
#pragma unroll
        for (int wv = 0; wv < 8; ++wv) {
            xa[2 * wv]     = asf(uu[wv] << 16);
            xa[2 * wv + 1] = asf(uu[wv] & 0xFFFF0000u);
            ya[2 * wv]     = asf(vv[wv] << 16);
            ya[2 * wv + 1] = asf(vv[wv] & 0xFFFF0000u);
        }
    }
    const int lane_j = ((kl >> 2) * 16 + ql) * 4 + (kl & 3);
#pragma unroll
    for (int h = 0; h < HH; ++h) {
        float t2 = xa[h] + ya[h] + bb;
        float sig = 1.f / (1.f + __expf(-t2));
        biasf[((b * HH + h) * 32 + kt) * (32 * 256) + qt * 256 + lane_j] = f2bf(sig);
    }
}

// ---------------------------------------------------------------------------
// Kernel 3: MFMA flash attention, swapped operands (round-3 verified).
// ---------------------------------------------------------------------------
__global__ __launch_bounds__(256, 4) void attn_k(
    const ushort_t* __restrict__ qbh, const ushort_t* __restrict__ kbh,
    const ushort_t* __restrict__ vtb, const ushort_t* __restrict__ biasf,
    ushort_t* __restrict__ attb)
{
    __shared__ ushort_t pst[4][16][40];     // per-wave P tiles [q][k32] (+pad)
    __shared__ float obuf[4][16][76];       // per-wave O^T partials [q][d]
    __shared__ float mt[4][16], lt[4][16];

    const int tid = threadIdx.x;
    const int wid = tid >> 6, lane = tid & 63;
    const int q = lane & 15, g = lane >> 4;
    const int qt = blockIdx.x;
    const int h = blockIdx.y, b = blockIdx.z;
    const int bh = b * HH + h;

    const ushort_t* Qp = qbh + (bh * NQS + qt * 16 + q) * DK + g * 8;
    short8v qf0 = *(const short8v*)Qp;
    short8v qf1 = *(const short8v*)(Qp + 32);

    f32x4 oacc[4] = {};
    float m = -1e30f, l = 0.f;

#pragma unroll 2
    for (int c = 0; c < 4; ++c) {
        const int kc = wid * 128 + c * 32;
        const ushort_t* Kp = kbh + (bh * NKS + kc + q) * DK + g * 8;
        short8v kf00 = *(const short8v*)(Kp);
        short8v kf01 = *(const short8v*)(Kp + 32);
        short8v kf10 = *(const short8v*)(Kp + 16 * DK);
        short8v kf11 = *(const short8v*)(Kp + 16 * DK + 32);

        f32x4 s0 = {0.f, 0.f, 0.f, 0.f};
        f32x4 s1 = {0.f, 0.f, 0.f, 0.f};
        s0 = __builtin_amdgcn_mfma_f32_16x16x32_bf16(kf00, qf0, s0, 0, 0, 0);
        s0 = __builtin_amdgcn_mfma_f32_16x16x32_bf16(kf01, qf1, s0, 0, 0, 0);
        s1 = __builtin_amdgcn_mfma_f32_16x16x32_bf16(kf10, qf0, s1, 0, 0, 0);
        s1 = __builtin_amdgcn_mfma_f32_16x16x32_bf16(kf11, qf1, s1, 0, 0, 0);

        // bias (fragment layout): tiles kt, kt+1
        const int kt = kc >> 4;
        uint2 b0 = *((const uint2*)(biasf + ((bh * 32 + kt) * 32 + qt) * 256) + lane);
        uint2 b1 = *((const uint2*)(biasf + ((bh * 32 + kt + 1) * 32 + qt) * 256) + lane);

        float sv[8];
        sv[0] = s0[0] + asf(b0.x << 16);
        sv[1] = s0[1] + asf(b0.x & 0xFFFF0000u);
        sv[2] = s0[2] + asf(b0.y << 16);
        sv[3] = s0[3] + asf(b0.y & 0xFFFF0000u);
        sv[4] = s1[0] + asf(b1.x << 16);
        sv[5] = s1[1] + asf(b1.x & 0xFFFF0000u);
        sv[6] = s1[2] + asf(b1.y << 16);
        sv[7] = s1[3] + asf(b1.y & 0xFFFF0000u);

        // row max across this lane's 8 + the 3 other g-lanes of column q
        float mc = fmaxf(fmaxf(fmaxf(sv[0], sv[1]), fmaxf(sv[2], sv[3])),
                         fmaxf(fmaxf(sv[4], sv[5]), fmaxf(sv[6], sv[7])));
        mc = fmaxf(mc, __shfl_xor(mc, 16));
        mc = fmaxf(mc, __shfl_xor(mc, 32));
        float mn = fmaxf(m, mc);

        float p[8], ps = 0.f;
#pragma unroll
        for (int j = 0; j < 8; ++j) { p[j] = __expf(sv[j] - mn); ps += p[j]; }
        float sc = __expf(m - mn);
        l = l * sc + ps;
        m = mn;
#pragma unroll
        for (int dt = 0; dt < 4; ++dt)
#pragma unroll
            for (int j = 0; j < 4; ++j) oacc[dt][j] *= sc;

        // P^T fragment via per-wave LDS tile
        ushort_t* prow = &pst[wid][q][0];
        *(unsigned*)(prow + 4 * g)          = pack2(p[0], p[1]);
        *(unsigned*)(prow + 4 * g + 2)      = pack2(p[2], p[3]);
        *(unsigned*)(prow + 16 + 4 * g)     = pack2(p[4], p[5]);
        *(unsigned*)(prow + 16 + 4 * g + 2) = pack2(p[6], p[7]);
        short8v pf = *(const short8v*)&pst[wid][q][8 * g];

        // O^T += V^T . P^T over this chunk's 32 k
        const ushort_t* Vp = vtb + (bh * DK + q) * NKS + kc + g * 8;
#pragma unroll
        for (int dt = 0; dt < 4; ++dt) {
            short8v vf = *(const short8v*)(Vp + dt * 16 * NKS);
            oacc[dt] = __builtin_amdgcn_mfma_f32_16x16x32_bf16(vf, pf, oacc[dt], 0, 0, 0);
        }
    }

    // intra-wave l across the 4 g-lanes of each q (m already shared)
    float lr = l + __shfl_xor(l, 16);
    lr = lr + __shfl_xor(lr, 32);
    if (lane < 16) { mt[wid][lane] = m; lt[wid][lane] = lr; }
#pragma unroll
    for (int dt = 0; dt < 4; ++dt)
#pragma unroll
        for (int j = 0; j < 4; ++j)
            obuf[wid][q][dt * 16 + 4 * g + j] = oacc[dt][j];
    __syncthreads();

    // merge 4 wave-partials: thread -> (q = tid>>4, d4 = (tid&15)*4)
    const int mq = tid >> 4, d4 = (tid & 15) * 4;
    float m0 = mt[0][mq], m1 = mt[1][mq], m2 = mt[2][mq], m3 = mt[3][mq];
    float ms = fmaxf(fmaxf(m0, m1), fmaxf(m2, m3));
    float e0 = __expf(m0 - ms), e1 = __expf(m1 - ms);
    float e2 = __expf(m2 - ms), e3 = __expf(m3 - ms);
    float denom = lt[0][mq] * e0 + lt[1][mq] * e1 + lt[2][mq] * e2 + lt[3][mq] * e3;
    float inv = 1.f / denom;
    float4 o0 = *(float4*)&obuf[0][mq][d4];
    float4 o1 = *(float4*)&obuf[1][mq][d4];
    float4 o2 = *(float4*)&obuf[2][mq][d4];
    float4 o3 = *(float4*)&obuf[3][mq][d4];
    float r0 = (o0.x * e0 + o1.x * e1 + o2.x * e2 + o3.x * e3) * inv;
    float r1 = (o0.y * e0 + o1.y * e1 + o2.y * e2 + o3.y * e3) * inv;
    float r2 = (o0.z * e0 + o1.z * e1 + o2.z * e2 + o3.z * e3) * inv;
    float r3 = (o0.w * e0 + o1.w * e1 + o2.w * e2 + o3.w * e3) * inv;
    uint2 ow;
    ow.x = pack2(r0, r1); ow.y = pack2(r2, r3);
    *reinterpret_cast<uint2*>(attb + (b * NQS + qt * 16 + mq) * DM + h * DK + d4) = ow;
}

// ---------------------------------------------------------------------------
// Kernel 4: output projection GEMM (A bf16 attb, B pre-transposed Wo bf16,
// plain fp32 [M][N] output). 64x64 tile, BK=64, 4 waves of 32x32.
// ---------------------------------------------------------------------------
__global__ __launch_bounds__(256) void ogemm_k(
    const ushort_t* __restrict__ Ah, const ushort_t* __restrict__ Bp,
    const float* __restrict__ bi, float* __restrict__ Yf)
{
    __shared__ ushort_t As[64][72];
    __shared__ ushort_t Bs[64][72];
    const int m0 = blockIdx.y * 64, n0 = blockIdx.x * 64;
    const int tid = threadIdx.x;
    const int lane = tid & 63, w = tid >> 6;
    const int wm = w >> 1, wn = w & 1;
    const int srow = tid >> 2, scg = (tid & 3) * 16;

    f32x4 acc[2][2] = {};
    uint4 arh0, arh1, brh0, brh1;

    auto loadA = [&](int kk) {
        const ushort_t* ap = Ah + (m0 + srow) * 1024 + kk + scg;
        arh0 = *(const uint4*)(ap);
        arh1 = *(const uint4*)(ap + 8);
    };
    auto loadB = [&](int kk) {
        const ushort_t* bp = Bp + (n0 + srow) * 1024 + kk + scg;
        brh0 = *(const uint4*)(bp);
        brh1 = *(const uint4*)(bp + 8);
    };
    loadA(0); loadB(0);

    const int fr = lane & 15;
    const int ko = (lane >> 4) * 8;

    for (int k0 = 0; k0 < 1024; k0 += 64) {
        __syncthreads();
        *(uint4*)&As[srow][scg]     = arh0;
        *(uint4*)&As[srow][scg + 8] = arh1;
        *(uint4*)&Bs[srow][scg]     = brh0;
        *(uint4*)&Bs[srow][scg + 8] = brh1;
        __syncthreads();
        if (k0 + 64 < 1024) { loadA(k0 + 64); loadB(k0 + 64); }
#pragma unroll
        for (int ks = 0; ks < 64; ks += 32) {
            short8v af0 = *(const short8v*)&As[wm * 32 + fr][ks + ko];
            short8v af1 = *(const short8v*)&As[wm * 32 + 16 + fr][ks + ko];
            short8v bf0 = *(const short8v*)&Bs[wn * 32 + fr][ks + ko];
            short8v bf1 = *(const short8v*)&Bs[wn * 32 + 16 + fr][ks + ko];
            acc[0][0] = __builtin_amdgcn_mfma_f32_16x16x32_bf16(af0, bf0, acc[0][0], 0, 0, 0);
            acc[0][1] = __builtin_amdgcn_mfma_f32_16x16x32_bf16(af0, bf1, acc[0][1], 0, 0, 0);
            acc[1][0] = __builtin_amdgcn_mfma_f32_16x16x32_bf16(af1, bf0, acc[1][0], 0, 0, 0);
            acc[1][1] = __builtin_amdgcn_mfma_f32_16x16x32_bf16(af1, bf1, acc[1][1], 0, 0, 0);
        }
    }

    const int cr = (lane >> 4) * 4;
    const int cc = lane & 15;
#pragma unroll
    for (int m = 0; m < 2; ++m) {
#pragma unroll
        for (int n = 0; n < 2; ++n) {
            int grow = m0 + wm * 32 + m * 16 + cr;
            int gcol = n0 + wn * 32 + n * 16 + cc;
            float bv = bi[gcol];
#pragma unroll
            for (int j = 0; j < 4; ++j)
                Yf[(grow + j) * 1024 + gcol] = acc[m][n][j] + bv;
        }
    }
}

// ---------------------------------------------------------------------------
extern "C" void kernel_launch(void* const* d_in, const int* in_sizes, int n_in,
                              void* d_out, int out_size, void* d_ws, size_t ws_size,
                              hipStream_t stream)
{
    const float* query = (const float*)d_in[0];
    const float* key   = (const float*)d_in[1];
    const float* value = (const float*)d_in[2];
    const float* qx    = (const float*)d_in[3];
    const float* qy    = (const float*)d_in[4];
    const float* kx    = (const float*)d_in[5];
    const float* ky    = (const float*)d_in[6];
    const float* Wq    = (const float*)d_in[7];
    const float* bq    = (const float*)d_in[8];
    const float* Wk    = (const float*)d_in[9];
    const float* bk    = (const float*)d_in[10];
    const float* Wv    = (const float*)d_in[11];
    const float* bv    = (const float*)d_in[12];
    const float* Wo    = (const float*)d_in[13];
    const float* bo    = (const float*)d_in[14];
    const float* xt    = (const float*)d_in[15];
    const float* yt    = (const float*)d_in[16];
    const float* Wb    = (const float*)d_in[17];
    const float* bbp   = (const float*)d_in[18];
    float* out = (float*)d_out;

    // ws layout — ALL offsets in ushort (bf16) units.
    ushort_t* xprojh = (ushort_t*)d_ws;                  //   640,064
    ushort_t* yprojh = xprojh + 640064;                  //   640,064
    ushort_t* biasf  = yprojh + 640064;                  // 8,388,608  (B,H,32,32,256)
    ushort_t* qbh    = biasf + 8388608;                  // 1,048,576  (B,H,512,64)
    ushort_t* kbh    = qbh + 1048576;                    // 1,048,576
    ushort_t* vtb    = kbh + 1048576;                    // 1,048,576  (B,H,64,512)
    ushort_t* attb   = vtb + 1048576;                    // 1,048,576  (B,512,1024)
    ushort_t* wot    = attb + 1048576;                   // 1,048,576

    fused1_k<<<dim3(K1_BLKS), dim3(256), 0, stream>>>(
        xt, yt, Wb, Wq, Wk, Wv, Wo, query, key, value, bq, bk, bv,
        xprojh, yprojh, wot, qbh, kbh, vtb);
    bias_k<<<dim3(2048), dim3(256), 0, stream>>>(
        xprojh, yprojh, qx, qy, kx, ky, bbp, biasf);
    attn_k<<<dim3(32, 16, 2), dim3(256), 0, stream>>>(
        qbh, kbh, vtb, biasf, attb);
    ogemm_k<<<dim3(16, 16), dim3(256), 0, stream>>>(
        attb, wot, bo, out);
}

// Round 15
// 78.303 us; speedup vs baseline: 1.4488x; 1.4488x over previous
//
#include <hip/hip_runtime.h>
#include <math.h>

#define HH 16
#define DM 1024
#define DK 64
#define NE 40001
#define NB 2
#define NQS 512
#define NKS 512

typedef unsigned short ushort_t;
typedef __attribute__((ext_vector_type(8))) short short8v;
typedef __attribute__((ext_vector_type(4))) float f32x4;

__device__ __forceinline__ ushort_t f2bf(float f) {
    union { float f; unsigned u; } v; v.f = f;
    unsigned r = v.u + 0x7FFFu + ((v.u >> 16) & 1u);
    return (ushort_t)(r >> 16);
}
__device__ __forceinline__ unsigned pack2(float a, float b) {
    return (unsigned)f2bf(a) | ((unsigned)f2bf(b) << 16);
}
__device__ __forceinline__ float asf(unsigned u) {
    union { unsigned u; float f; } v; v.u = u; return v.f;
}

// ---------------------------------------------------------------------------
// Kernel A (prep): persistent grid-stride (round-11 best-known form).
// prep is pinned at ~40us across 6 structurally different implementations
// (r6-r14) — environmental read-path limit, not access-pattern.
//   blocks [0, 1024)      : proj — grid-stride over 5.12M float4
//   blocks [1024, 1536)   : W transpose-convert, 2 LDS-tiles per block
//   blocks [1536, 1792)   : QKV fp32->bf16, 12 float4 per thread
// ---------------------------------------------------------------------------
#define PROJ_F4   (NE * 64)            // 2,560,064 float4 per table
#define PROJ_TOT  (2 * PROJ_F4)        // 5,120,128
#define PREP_PROJ_BLKS 1024
#define PREP_WT_BLKS   512
#define PREP_QKV_BLKS  256

__global__ __launch_bounds__(256) void prep_k(
    const float* __restrict__ xt, const float* __restrict__ yt,
    const float* __restrict__ Wb,
    const float* __restrict__ wq, const float* __restrict__ wk,
    const float* __restrict__ wv, const float* __restrict__ wo,
    const float* __restrict__ xq, const float* __restrict__ xk, const float* __restrict__ xv,
    ushort_t* __restrict__ xproj, ushort_t* __restrict__ yproj,
    ushort_t* __restrict__ wqt, ushort_t* __restrict__ wkt,
    ushort_t* __restrict__ wvt, ushort_t* __restrict__ wot,
    ushort_t* __restrict__ qc, ushort_t* __restrict__ kc, ushort_t* __restrict__ vc)
{
    __shared__ float ls[64][68];
    const int bid = blockIdx.x;
    const int tid = threadIdx.x;

    if (bid < PREP_PROJ_BLKS) {
        // ---------- proj: grid-stride streaming + 4-lane shuffle reduce ----------
        const int c = tid & 3;
        const float4 wq4 = ((const float4*)Wb)[c];
#pragma unroll 4
        for (int f4 = bid * 256 + tid; f4 < PROJ_TOT; f4 += PREP_PROJ_BLKS * 256) {
            const int tsel = (f4 >= PROJ_F4);
            const int g = tsel ? f4 - PROJ_F4 : f4;
            const float* tab = tsel ? yt : xt;
            float4 v = ((const float4*)tab)[g];
            float p = v.x * wq4.x + v.y * wq4.y + v.z * wq4.z + v.w * wq4.w;
            p += __shfl_xor(p, 1);
            p += __shfl_xor(p, 2);                 // full 16-elem dot in all 4 lanes
            if (c == 0) {
                ushort_t* dst = tsel ? yproj : xproj;
                const int i = g >> 6, h = (g >> 2) & 15;
                dst[i * 16 + h] = f2bf(p);
            }
        }
    } else if (bid < PREP_PROJ_BLKS + PREP_WT_BLKS) {
        // ---------- weight transpose-convert via LDS, 2 tiles per block ----------
        const int b0 = bid - PREP_PROJ_BLKS;       // 0..511
#pragma unroll
        for (int it = 0; it < 2; ++it) {
            const int t = b0 + it * PREP_WT_BLKS;  // 0..1023
            const int z = t >> 8;
            const int rem = t & 255;
            const int k0 = (rem >> 4) * 64, n0 = (rem & 15) * 64;
            const float* w = (z == 0) ? wq : ((z == 1) ? wk : ((z == 2) ? wv : wo));
            ushort_t* wt = (z == 0) ? wqt : ((z == 1) ? wkt : ((z == 2) ? wvt : wot));

            if (it) __syncthreads();               // protect LDS reuse
#pragma unroll
            for (int j = 0; j < 4; ++j) {
                int r = (tid >> 4) + j * 16;
                int c2 = (tid & 15) * 4;
                float4 v = *(const float4*)(w + (k0 + r) * 1024 + n0 + c2);
                *(float4*)&ls[r][c2] = v;
            }
            __syncthreads();

            const int n = tid >> 2, kq = (tid & 3) * 16;
            float e[16];
#pragma unroll
            for (int j = 0; j < 16; ++j) e[j] = ls[kq + j][n];
            uint4 o0, o1;
            o0.x = pack2(e[0], e[1]);   o0.y = pack2(e[2], e[3]);
            o0.z = pack2(e[4], e[5]);   o0.w = pack2(e[6], e[7]);
            o1.x = pack2(e[8], e[9]);   o1.y = pack2(e[10], e[11]);
            o1.z = pack2(e[12], e[13]); o1.w = pack2(e[14], e[15]);
            ushort_t* dp = wt + (n0 + n) * 1024 + k0 + kq;
            *(uint4*)(dp)     = o0;
            *(uint4*)(dp + 8) = o1;
        }
    } else {
        // ---------- QKV fp32 -> bf16, grid-stride (12 float4 / thread) ----------
        const int b0 = bid - (PREP_PROJ_BLKS + PREP_WT_BLKS);   // 0..255
#pragma unroll 4
        for (int f4 = b0 * 256 + tid; f4 < 786432; f4 += PREP_QKV_BLKS * 256) {
            const int z = f4 >> 18;                // 262144 float4 per tensor
            const int g = f4 & 262143;
            const float* src = (z == 0) ? xq : ((z == 1) ? xk : xv);
            ushort_t* dst = (z == 0) ? qc : ((z == 1) ? kc : vc);
            float4 a = ((const float4*)src)[g];
            uint2 o;
            o.x = pack2(a.x, a.y); o.y = pack2(a.z, a.w);
            *reinterpret_cast<uint2*>(dst + g * 4) = o;
        }
    }
}

// ---------------------------------------------------------------------------
// Kernel B (biasqkv): fused QKV MFMA GEMM (pure bf16 A) + bias precompute.
//   blocks [0, 768)       : GEMM — z=bid>>8 in {Q,K,V}
//   blocks [768, 768+2048): bias in MFMA-fragment layout (round-3 verified)
// ---------------------------------------------------------------------------
__global__ __launch_bounds__(256, 6) void biasqkv_k(
    const ushort_t* __restrict__ A0, const ushort_t* __restrict__ A1, const ushort_t* __restrict__ A2,
    const ushort_t* __restrict__ B0, const ushort_t* __restrict__ B1, const ushort_t* __restrict__ B2,
    const float* __restrict__ bi0, const float* __restrict__ bi1, const float* __restrict__ bi2,
    ushort_t* __restrict__ Yh0, ushort_t* __restrict__ Yh1, ushort_t* __restrict__ Yh2,
    const ushort_t* __restrict__ xproj, const ushort_t* __restrict__ yproj,
    const float* __restrict__ qx, const float* __restrict__ qy,
    const float* __restrict__ kx, const float* __restrict__ ky,
    const float* __restrict__ bbp,
    ushort_t* __restrict__ biasf)
{
    __shared__ ushort_t As[64][72];
    __shared__ ushort_t Bs[64][72];
    const int bid = blockIdx.x;
    const int tid = threadIdx.x;

    if (bid < 768) {
        // ---------------- GEMM path (bf16 A) ----------------
        const int z = bid >> 8, by = (bid >> 4) & 15, bx = bid & 15;
        const ushort_t* Ah = (z == 0) ? A0 : ((z == 1) ? A1 : A2);
        const ushort_t* Bp = (z == 0) ? B0 : ((z == 1) ? B1 : B2);
        const float* bi = (z == 0) ? bi0 : ((z == 1) ? bi1 : bi2);
        ushort_t* Yh = (z == 0) ? Yh0 : ((z == 1) ? Yh1 : Yh2);
        const int m0 = by * 64, n0 = bx * 64;
        const int lane = tid & 63, w = tid >> 6;
        const int wm = w >> 1, wn = w & 1;
        const int srow = tid >> 2, scg = (tid & 3) * 16;

        f32x4 acc[2][2] = {};
        uint4 arh0, arh1, brh0, brh1;

        auto loadA = [&](int kk) {
            const ushort_t* ap = Ah + (m0 + srow) * 1024 + kk + scg;
            arh0 = *(const uint4*)(ap);
            arh1 = *(const uint4*)(ap + 8);
        };
        auto loadB = [&](int kk) {
            const ushort_t* bp = Bp + (n0 + srow) * 1024 + kk + scg;
            brh0 = *(const uint4*)(bp);
            brh1 = *(const uint4*)(bp + 8);
        };
        loadA(0); loadB(0);

        const int fr = lane & 15;            // frag row/col within 16
        const int ko = (lane >> 4) * 8;      // k offset within 32

        for (int k0 = 0; k0 < 1024; k0 += 64) {
            __syncthreads();
            *(uint4*)&As[srow][scg]     = arh0;
            *(uint4*)&As[srow][scg + 8] = arh1;
            *(uint4*)&Bs[srow][scg]     = brh0;
            *(uint4*)&Bs[srow][scg + 8] = brh1;
            __syncthreads();
            if (k0 + 64 < 1024) { loadA(k0 + 64); loadB(k0 + 64); }
#pragma unroll
            for (int ks = 0; ks < 64; ks += 32) {
                short8v af0 = *(const short8v*)&As[wm * 32 + fr][ks + ko];
                short8v af1 = *(const short8v*)&As[wm * 32 + 16 + fr][ks + ko];
                short8v bf0 = *(const short8v*)&Bs[wn * 32 + fr][ks + ko];
                short8v bf1 = *(const short8v*)&Bs[wn * 32 + 16 + fr][ks + ko];
                acc[0][0] = __builtin_amdgcn_mfma_f32_16x16x32_bf16(af0, bf0, acc[0][0], 0, 0, 0);
                acc[0][1] = __builtin_amdgcn_mfma_f32_16x16x32_bf16(af0, bf1, acc[0][1], 0, 0, 0);
                acc[1][0] = __builtin_amdgcn_mfma_f32_16x16x32_bf16(af1, bf0, acc[1][0], 0, 0, 0);
                acc[1][1] = __builtin_amdgcn_mfma_f32_16x16x32_bf16(af1, bf1, acc[1][1], 0, 0, 0);
            }
        }

        const int cr = (lane >> 4) * 4;
        const int cc = lane & 15;
#pragma unroll
        for (int m = 0; m < 2; ++m) {
#pragma unroll
            for (int n = 0; n < 2; ++n) {
                int grow = m0 + wm * 32 + m * 16 + cr;
                int gcol = n0 + wn * 32 + n * 16 + cc;
                float bv = bi[gcol];
                int hh = gcol >> 6, dd = gcol & 63;
                if (z == 0) {
#pragma unroll
                    for (int j = 0; j < 4; ++j) {
                        int r = grow + j, bb_ = r >> 9, nn = r & 511;
                        Yh[((bb_ * HH + hh) * NQS + nn) * DK + dd] = f2bf(acc[m][n][j] + bv);
                    }
                } else if (z == 1) {
                    // K pre-scaled by 1/sqrt(DK) = 0.125 (exact power-of-two)
#pragma unroll
                    for (int j = 0; j < 4; ++j) {
                        int r = grow + j, bb_ = r >> 9, nn = r & 511;
                        Yh[((bb_ * HH + hh) * NQS + nn) * DK + dd] = f2bf((acc[m][n][j] + bv) * 0.125f);
                    }
                } else {
                    // V: (B,H,64,N) bf16 transposed
#pragma unroll
                    for (int j = 0; j < 4; ++j) {
                        int r = grow + j, bb_ = r >> 9, nn = r & 511;
                        Yh[((bb_ * HH + hh) * DK + dd) * NKS + nn] = f2bf(acc[m][n][j] + bv);
                    }
                }
            }
        }
    } else {
        // ---------------- bias path ----------------
        const int r = bid - 768;               // 0..2047
        const int b = r >> 10;
        const int kt = (r >> 5) & 31, qt = r & 31;
        const int ql = tid & 15, kl = tid >> 4;
        const int qg = qt * 16 + ql, kg = kt * 16 + kl;

        float dx = qx[b * NKS + kg] - kx[b * NQS + qg];
        float dy = qy[b * NKS + kg] - ky[b * NQS + qg];
        int ix = (int)rintf((fminf(fmaxf(dx, -1000.f), 1000.f) + 1000.f) * 20.f);
        int iy = (int)rintf((fminf(fmaxf(dy, -1000.f), 1000.f) + 1000.f) * 20.f);
        const float bb = bbp[0];

        uint4 xw0 = *(const uint4*)(xproj + ix * 16);
        uint4 xw1 = *(const uint4*)(xproj + ix * 16 + 8);
        uint4 yw0 = *(const uint4*)(yproj + iy * 16);
        uint4 yw1 = *(const uint4*)(yproj + iy * 16 + 8);

        float xa[16], ya[16];
        {
            unsigned u[8] = {xw0.x, xw0.y, xw0.z, xw0.w, xw1.x, xw1.y, xw1.z, xw1.w};
            unsigned v[8] = {yw0.x, yw0.y, yw0.z, yw0.w, yw1.x, yw1.y, yw1.z, yw1.w};
#pragma unroll
            for (int wv = 0; wv < 8; ++wv) {
                xa[2 * wv]     = asf(u[wv] << 16);
                xa[2 * wv + 1] = asf(u[wv] & 0xFFFF0000u);
                ya[2 * wv]     = asf(v[wv] << 16);
                ya[2 * wv + 1] = asf(v[wv] & 0xFFFF0000u);
            }
        }
        const int lane_j = ((kl >> 2) * 16 + ql) * 4 + (kl & 3);
#pragma unroll
        for (int h = 0; h < HH; ++h) {
            float t2 = xa[h] + ya[h] + bb;
            float sig = 1.f / (1.f + __expf(-t2));
            biasf[((b * HH + h) * 32 + kt) * (32 * 256) + qt * 256 + lane_j] = f2bf(sig);
        }
    }
}

// ---------------------------------------------------------------------------
// Kernel C: MFMA flash attention, swapped operands (round-3 verified).
// ---------------------------------------------------------------------------
__global__ __launch_bounds__(256, 4) void attn_k(
    const ushort_t* __restrict__ qbh, const ushort_t* __restrict__ kbh,
    const ushort_t* __restrict__ vtb, const ushort_t* __restrict__ biasf,
    ushort_t* __restrict__ attb)
{
    __shared__ ushort_t pst[4][16][40];     // per-wave P tiles [q][k32] (+pad)
    __shared__ float obuf[4][16][76];       // per-wave O^T partials [q][d]
    __shared__ float mt[4][16], lt[4][16];

    const int tid = threadIdx.x;
    const int wid = tid >> 6, lane = tid & 63;
    const int q = lane & 15, g = lane >> 4;
    const int qt = blockIdx.x;
    const int h = blockIdx.y, b = blockIdx.z;
    const int bh = b * HH + h;

    const ushort_t* Qp = qbh + (bh * NQS + qt * 16 + q) * DK + g * 8;
    short8v qf0 = *(const short8v*)Qp;
    short8v qf1 = *(const short8v*)(Qp + 32);

    f32x4 oacc[4] = {};
    float m = -1e30f, l = 0.f;

#pragma unroll 2
    for (int c = 0; c < 4; ++c) {
        const int kc = wid * 128 + c * 32;
        const ushort_t* Kp = kbh + (bh * NKS + kc + q) * DK + g * 8;
        short8v kf00 = *(const short8v*)(Kp);
        short8v kf01 = *(const short8v*)(Kp + 32);
        short8v kf10 = *(const short8v*)(Kp + 16 * DK);
        short8v kf11 = *(const short8v*)(Kp + 16 * DK + 32);

        f32x4 s0 = {0.f, 0.f, 0.f, 0.f};
        f32x4 s1 = {0.f, 0.f, 0.f, 0.f};
        s0 = __builtin_amdgcn_mfma_f32_16x16x32_bf16(kf00, qf0, s0, 0, 0, 0);
        s0 = __builtin_amdgcn_mfma_f32_16x16x32_bf16(kf01, qf1, s0, 0, 0, 0);
        s1 = __builtin_amdgcn_mfma_f32_16x16x32_bf16(kf10, qf0, s1, 0, 0, 0);
        s1 = __builtin_amdgcn_mfma_f32_16x16x32_bf16(kf11, qf1, s1, 0, 0, 0);

        // bias (fragment layout): tiles kt, kt+1
        const int kt = kc >> 4;
        uint2 b0 = *((const uint2*)(biasf + ((bh * 32 + kt) * 32 + qt) * 256) + lane);
        uint2 b1 = *((const uint2*)(biasf + ((bh * 32 + kt + 1) * 32 + qt) * 256) + lane);

        float sv[8];
        sv[0] = s0[0] + asf(b0.x << 16);
        sv[1] = s0[1] + asf(b0.x & 0xFFFF0000u);
        sv[2] = s0[2] + asf(b0.y << 16);
        sv[3] = s0[3] + asf(b0.y & 0xFFFF0000u);
        sv[4] = s1[0] + asf(b1.x << 16);
        sv[5] = s1[1] + asf(b1.x & 0xFFFF0000u);
        sv[6] = s1[2] + asf(b1.y << 16);
        sv[7] = s1[3] + asf(b1.y & 0xFFFF0000u);

        // row max across this lane's 8 + the 3 other g-lanes of column q
        float mc = fmaxf(fmaxf(fmaxf(sv[0], sv[1]), fmaxf(sv[2], sv[3])),
                         fmaxf(fmaxf(sv[4], sv[5]), fmaxf(sv[6], sv[7])));
        mc = fmaxf(mc, __shfl_xor(mc, 16));
        mc = fmaxf(mc, __shfl_xor(mc, 32));
        float mn = fmaxf(m, mc);

        float p[8], ps = 0.f;
#pragma unroll
        for (int j = 0; j < 8; ++j) { p[j] = __expf(sv[j] - mn); ps += p[j]; }
        float sc = __expf(m - mn);
        l = l * sc + ps;
        m = mn;
#pragma unroll
        for (int dt = 0; dt < 4; ++dt)
#pragma unroll
            for (int j = 0; j < 4; ++j) oacc[dt][j] *= sc;

        // P^T fragment via per-wave LDS tile
        ushort_t* prow = &pst[wid][q][0];
        *(unsigned*)(prow + 4 * g)          = pack2(p[0], p[1]);
        *(unsigned*)(prow + 4 * g + 2)      = pack2(p[2], p[3]);
        *(unsigned*)(prow + 16 + 4 * g)     = pack2(p[4], p[5]);
        *(unsigned*)(prow + 16 + 4 * g + 2) = pack2(p[6], p[7]);
        short8v pf = *(const short8v*)&pst[wid][q][8 * g];

        // O^T += V^T . P^T over this chunk's 32 k
        const ushort_t* Vp = vtb + (bh * DK + q) * NKS + kc + g * 8;
#pragma unroll
        for (int dt = 0; dt < 4; ++dt) {
            short8v vf = *(const short8v*)(Vp + dt * 16 * NKS);
            oacc[dt] = __builtin_amdgcn_mfma_f32_16x16x32_bf16(vf, pf, oacc[dt], 0, 0, 0);
        }
    }

    // intra-wave l across the 4 g-lanes of each q (m already shared)
    float lr = l + __shfl_xor(l, 16);
    lr = lr + __shfl_xor(lr, 32);
    if (lane < 16) { mt[wid][lane] = m; lt[wid][lane] = lr; }
#pragma unroll
    for (int dt = 0; dt < 4; ++dt)
#pragma unroll
        for (int j = 0; j < 4; ++j)
            obuf[wid][q][dt * 16 + 4 * g + j] = oacc[dt][j];
    __syncthreads();

    // merge 4 wave-partials: thread -> (q = tid>>4, d4 = (tid&15)*4)
    const int mq = tid >> 4, d4 = (tid & 15) * 4;
    float m0 = mt[0][mq], m1 = mt[1][mq], m2 = mt[2][mq], m3 = mt[3][mq];
    float ms = fmaxf(fmaxf(m0, m1), fmaxf(m2, m3));
    float e0 = __expf(m0 - ms), e1 = __expf(m1 - ms);
    float e2 = __expf(m2 - ms), e3 = __expf(m3 - ms);
    float denom = lt[0][mq] * e0 + lt[1][mq] * e1 + lt[2][mq] * e2 + lt[3][mq] * e3;
    float inv = 1.f / denom;
    float4 o0 = *(float4*)&obuf[0][mq][d4];
    float4 o1 = *(float4*)&obuf[1][mq][d4];
    float4 o2 = *(float4*)&obuf[2][mq][d4];
    float4 o3 = *(float4*)&obuf[3][mq][d4];
    float r0 = (o0.x * e0 + o1.x * e1 + o2.x * e2 + o3.x * e3) * inv;
    float r1 = (o0.y * e0 + o1.y * e1 + o2.y * e2 + o3.y * e3) * inv;
    float r2 = (o0.z * e0 + o1.z * e1 + o2.z * e2 + o3.z * e3) * inv;
    float r3 = (o0.w * e0 + o1.w * e1 + o2.w * e2 + o3.w * e3) * inv;
    uint2 ow;
    ow.x = pack2(r0, r1); ow.y = pack2(r2, r3);
    *reinterpret_cast<uint2*>(attb + (b * NQS + qt * 16 + mq) * DM + h * DK + d4) = ow;
}

// ---------------------------------------------------------------------------
// Kernel D: output projection GEMM (A bf16 attb, B pre-transposed Wo bf16,
// plain fp32 [M][N] output). 64x64 tile, BK=64, 4 waves of 32x32.
// ---------------------------------------------------------------------------
__global__ __launch_bounds__(256) void ogemm_k(
    const ushort_t* __restrict__ Ah, const ushort_t* __restrict__ Bp,
    const float* __restrict__ bi, float* __restrict__ Yf)
{
    __shared__ ushort_t As[64][72];
    __shared__ ushort_t Bs[64][72];
    const int m0 = blockIdx.y * 64, n0 = blockIdx.x * 64;
    const int tid = threadIdx.x;
    const int lane = tid & 63, w = tid >> 6;
    const int wm = w >> 1, wn = w & 1;
    const int srow = tid >> 2, scg = (tid & 3) * 16;

    f32x4 acc[2][2] = {};
    uint4 arh0, arh1, brh0, brh1;

    auto loadA = [&](int kk) {
        const ushort_t* ap = Ah + (m0 + srow) * 1024 + kk + scg;
        arh0 = *(const uint4*)(ap);
        arh1 = *(const uint4*)(ap + 8);
    };
    auto loadB = [&](int kk) {
        const ushort_t* bp = Bp + (n0 + srow) * 1024 + kk + scg;
        brh0 = *(const uint4*)(bp);
        brh1 = *(const uint4*)(bp + 8);
    };
    loadA(0); loadB(0);

    const int fr = lane & 15;
    const int ko = (lane >> 4) * 8;

    for (int k0 = 0; k0 < 1024; k0 += 64) {
        __syncthreads();
        *(uint4*)&As[srow][scg]     = arh0;
        *(uint4*)&As[srow][scg + 8] = arh1;
        *(uint4*)&Bs[srow][scg]     = brh0;
        *(uint4*)&Bs[srow][scg + 8] = brh1;
        __syncthreads();
        if (k0 + 64 < 1024) { loadA(k0 + 64); loadB(k0 + 64); }
#pragma unroll
        for (int ks = 0; ks < 64; ks += 32) {
            short8v af0 = *(const short8v*)&As[wm * 32 + fr][ks + ko];
            short8v af1 = *(const short8v*)&As[wm * 32 + 16 + fr][ks + ko];
            short8v bf0 = *(const short8v*)&Bs[wn * 32 + fr][ks + ko];
            short8v bf1 = *(const short8v*)&Bs[wn * 32 + 16 + fr][ks + ko];
            acc[0][0] = __builtin_amdgcn_mfma_f32_16x16x32_bf16(af0, bf0, acc[0][0], 0, 0, 0);
            acc[0][1] = __builtin_amdgcn_mfma_f32_16x16x32_bf16(af0, bf1, acc[0][1], 0, 0, 0);
            acc[1][0] = __builtin_amdgcn_mfma_f32_16x16x32_bf16(af1, bf0, acc[1][0], 0, 0, 0);
            acc[1][1] = __builtin_amdgcn_mfma_f32_16x16x32_bf16(af1, bf1, acc[1][1], 0, 0, 0);
        }
    }

    const int cr = (lane >> 4) * 4;
    const int cc = lane & 15;
#pragma unroll
    for (int m = 0; m < 2; ++m) {
#pragma unroll
        for (int n = 0; n < 2; ++n) {
            int grow = m0 + wm * 32 + m * 16 + cr;
            int gcol = n0 + wn * 32 + n * 16 + cc;
            float bv = bi[gcol];
#pragma unroll
            for (int j = 0; j < 4; ++j)
                Yf[(grow + j) * 1024 + gcol] = acc[m][n][j] + bv;
        }
    }
}

// ---------------------------------------------------------------------------
extern "C" void kernel_launch(void* const* d_in, const int* in_sizes, int n_in,
                              void* d_out, int out_size, void* d_ws, size_t ws_size,
                              hipStream_t stream)
{
    const float* query = (const float*)d_in[0];
    const float* key   = (const float*)d_in[1];
    const float* value = (const float*)d_in[2];
    const float* qx    = (const float*)d_in[3];
    const float* qy    = (const float*)d_in[4];
    const float* kx    = (const float*)d_in[5];
    const float* ky    = (const float*)d_in[6];
    const float* Wq    = (const float*)d_in[7];
    const float* bq    = (const float*)d_in[8];
    const float* Wk    = (const float*)d_in[9];
    const float* bk    = (const float*)d_in[10];
    const float* Wv    = (const float*)d_in[11];
    const float* bv    = (const float*)d_in[12];
    const float* Wo    = (const float*)d_in[13];
    const float* bo    = (const float*)d_in[14];
    const float* xt    = (const float*)d_in[15];
    const float* yt    = (const float*)d_in[16];
    const float* Wb    = (const float*)d_in[17];
    const float* bbp   = (const float*)d_in[18];
    float* out = (float*)d_out;

    // ws layout — ALL offsets in ushort (bf16) units.
    ushort_t* xprojh = (ushort_t*)d_ws;                  //   640,064
    ushort_t* yprojh = xprojh + 640064;                  //   640,064
    ushort_t* biasf  = yprojh + 640064;                  // 8,388,608  (B,H,32,32,256)
    ushort_t* qbh    = biasf + 8388608;                  // 1,048,576  (B,H,512,64)
    ushort_t* kbh    = qbh + 1048576;                    // 1,048,576
    ushort_t* vtb    = kbh + 1048576;                    // 1,048,576  (B,H,64,512)
    ushort_t* attb   = vtb + 1048576;                    // 1,048,576  (B,512,1024)
    ushort_t* wqt    = attb + 1048576;                   // 1,048,576 each
    ushort_t* wkt    = wqt + 1048576;
    ushort_t* wvt    = wkt + 1048576;
    ushort_t* wot    = wvt + 1048576;
    ushort_t* qc     = wot + 1048576;                    // 1,048,576 each (bf16 QKV inputs)
    ushort_t* kc     = qc + 1048576;
    ushort_t* vc     = kc + 1048576;

    prep_k<<<dim3(PREP_PROJ_BLKS + PREP_WT_BLKS + PREP_QKV_BLKS), dim3(256), 0, stream>>>(
        xt, yt, Wb, Wq, Wk, Wv, Wo, query, key, value,
        xprojh, yprojh, wqt, wkt, wvt, wot, qc, kc, vc);
    biasqkv_k<<<dim3(768 + 2048), dim3(256), 0, stream>>>(
        qc, kc, vc, wqt, wkt, wvt, bq, bk, bv, qbh, kbh, vtb,
        xprojh, yprojh, qx, qy, kx, ky, bbp, biasf);
    attn_k<<<dim3(32, 16, 2), dim3(256), 0, stream>>>(
        qbh, kbh, vtb, biasf, attb);
    ogemm_k<<<dim3(16, 16), dim3(256), 0, stream>>>(
        attb, wot, bo, out);
}